// Round 1
// baseline (319.578 us; speedup 1.0000x reference)
//
#include <hip/hip_runtime.h>
#include <math.h>

// KGAT attention aggregation, MI355X.
// Key algebraic simplification: fc1->fc2 with no activation collapses to a
// single linear functional: logits = concat . (W1@W2) + (b1.W2 + b2).
// Compute becomes negligible; kernel is HBM-bound (~341 MB traffic).

#define DIM 128
#define KN 5

// Fold W1 [384,128] @ W2 [128] -> w[384], and c = b1.W2 + b2 -> ws[384].
__global__ void kgat_prep(const float* __restrict__ W1,
                          const float* __restrict__ b1,
                          const float* __restrict__ W2,
                          const float* __restrict__ b2,
                          float* __restrict__ ws) {
    int t = threadIdx.x;  // 0..383
    if (t < 3 * DIM) {
        float s = 0.f;
        #pragma unroll 8
        for (int a = 0; a < DIM; ++a) s += W1[t * DIM + a] * W2[a];
        ws[t] = s;
    }
    if (t == 0) {
        float c = b2[0];
        for (int a = 0; a < DIM; ++a) c += b1[a] * W2[a];
        ws[3 * DIM] = c;
    }
}

// One wave (64 lanes) per (b,n) row. Lane i owns elements [2i, 2i+1] of D=128.
__global__ __launch_bounds__(256) void kgat_main(
    const float* __restrict__ ent,   // [P, 128]
    const float* __restrict__ ne,    // [P, 5, 128]
    const float* __restrict__ nr,    // [P, 5, 128]
    const float* __restrict__ ws,    // w[384], c
    float* __restrict__ out,         // [P, 256]
    int P)
{
    const int wave = threadIdx.x >> 6;
    const int lane = threadIdx.x & 63;
    const int p = blockIdx.x * 4 + wave;
    if (p >= P) return;

    const int d2 = 2 * lane;
    // broadcast weights (L1/L2-resident, same for all blocks)
    const float2 we  = *(const float2*)(ws + d2);
    const float2 wne = *(const float2*)(ws + DIM + d2);
    const float2 wnr = *(const float2*)(ws + 2 * DIM + d2);
    const float  c   = ws[3 * DIM];

    const size_t rowE = (size_t)p * DIM + d2;
    const size_t rowK = ((size_t)p * KN) * DIM + d2;

    const float2 e2 = *(const float2*)(ent + rowE);
    float2 ne2[KN], nr2[KN];
    #pragma unroll
    for (int k = 0; k < KN; ++k) {
        ne2[k] = *(const float2*)(ne + rowK + (size_t)k * DIM);
        nr2[k] = *(const float2*)(nr + rowK + (size_t)k * DIM);
    }

    // per-lane partial dot products
    float red[KN + 1];
    red[0] = e2.x * we.x + e2.y * we.y;
    #pragma unroll
    for (int k = 0; k < KN; ++k)
        red[k + 1] = ne2[k].x * wne.x + ne2[k].y * wne.y
                   + nr2[k].x * wnr.x + nr2[k].y * wnr.y;

    // butterfly reduction across the 64-lane wave (all lanes end with the sum)
    #pragma unroll
    for (int j = 0; j < KN + 1; ++j) {
        float v = red[j];
        #pragma unroll
        for (int off = 32; off >= 1; off >>= 1)
            v += __shfl_xor(v, off, 64);
        red[j] = v;
    }

    // softmax over K=5 (redundant in every lane; all lanes agree)
    float logit[KN];
    float m = -INFINITY;
    #pragma unroll
    for (int k = 0; k < KN; ++k) {
        logit[k] = red[k + 1] + red[0] + c;
        m = fmaxf(m, logit[k]);
    }
    float ex[KN], s = 0.f;
    #pragma unroll
    for (int k = 0; k < KN; ++k) { ex[k] = __expf(logit[k] - m); s += ex[k]; }
    const float inv = 1.f / s;

    // attention-weighted neighbor sum from registers (no re-read of ne)
    float2 acc = {0.f, 0.f};
    #pragma unroll
    for (int k = 0; k < KN; ++k) {
        const float a = ex[k] * inv;
        acc.x += a * ne2[k].x;
        acc.y += a * ne2[k].y;
    }

    float* orow = out + (size_t)p * (2 * DIM);
    *(float2*)(orow + d2) = e2;           // copy entity embedding
    *(float2*)(orow + DIM + d2) = acc;    // attention aggregate
}

extern "C" void kernel_launch(void* const* d_in, const int* in_sizes, int n_in,
                              void* d_out, int out_size, void* d_ws, size_t ws_size,
                              hipStream_t stream) {
    const float* ent = (const float*)d_in[0];
    const float* ne  = (const float*)d_in[1];
    const float* nr  = (const float*)d_in[2];
    const float* W1  = (const float*)d_in[3];
    const float* b1  = (const float*)d_in[4];
    const float* W2  = (const float*)d_in[5];
    const float* b2  = (const float*)d_in[6];
    float* out = (float*)d_out;
    float* ws  = (float*)d_ws;

    const int P = in_sizes[0] / DIM;  // B*N rows

    kgat_prep<<<1, 384, 0, stream>>>(W1, b1, W2, b2, ws);
    const int blocks = (P + 3) / 4;  // 4 waves per 256-thread block
    kgat_main<<<blocks, 256, 0, stream>>>(ent, ne, nr, ws, out, P);
}

// Round 3
// 313.062 us; speedup vs baseline: 1.0208x; 1.0208x over previous
//
#include <hip/hip_runtime.h>
#include <math.h>

// KGAT attention aggregation, MI355X.
// fc1->fc2 with no activation collapses to one linear functional:
//   logit = concat . (W1@W2) + (b1.W2 + b2)
// Kernel is HBM-bound (~341 MB logical traffic, floor ~54 us).
// R3: float4 loads, 32 lanes per row (2 rows/wave), 5-step butterfly,
//     parallel prep kernel, nontemporal output stores (native vec type).

#define DIM 128
#define KN 5

typedef float nfloat4 __attribute__((ext_vector_type(4)));  // native vec for builtins

__device__ __forceinline__ float dot4(nfloat4 a, nfloat4 b) {
    return a.x * b.x + a.y * b.y + a.z * b.z + a.w * b.w;
}

// One wave per output element of w = W1@W2 (384 outputs) + one wave for c.
__global__ __launch_bounds__(256) void kgat_prep(
    const float* __restrict__ W1,   // [384,128]
    const float* __restrict__ b1,   // [128]
    const float* __restrict__ W2,   // [128]
    const float* __restrict__ b2,   // [1]
    float* __restrict__ ws)         // w[384], c
{
    const int gw = blockIdx.x * 4 + (threadIdx.x >> 6);
    const int lane = threadIdx.x & 63;
    if (gw < 3 * DIM) {
        const int t = gw;
        const float2 w1 = *(const float2*)(W1 + (size_t)t * DIM + 2 * lane);
        const float2 w2 = *(const float2*)(W2 + 2 * lane);
        float v = w1.x * w2.x + w1.y * w2.y;
        #pragma unroll
        for (int off = 32; off >= 1; off >>= 1) v += __shfl_xor(v, off, 64);
        if (lane == 0) ws[t] = v;
    } else if (gw == 3 * DIM) {
        const float2 bb = *(const float2*)(b1 + 2 * lane);
        const float2 w2 = *(const float2*)(W2 + 2 * lane);
        float v = bb.x * w2.x + bb.y * w2.y;
        #pragma unroll
        for (int off = 32; off >= 1; off >>= 1) v += __shfl_xor(v, off, 64);
        if (lane == 0) ws[3 * DIM] = v + b2[0];
    }
}

// 32 lanes per (b,n) row; each wave handles 2 rows (half-waves independent).
__global__ __launch_bounds__(256) void kgat_main(
    const float* __restrict__ ent,   // [P, 128]
    const float* __restrict__ ne,    // [P, 5, 128]
    const float* __restrict__ nr,    // [P, 5, 128]
    const float* __restrict__ ws,    // w[384], c
    float* __restrict__ out,         // [P, 256]
    int P)
{
    const int wave = threadIdx.x >> 6;
    const int lane = threadIdx.x & 63;
    const int half = lane >> 5;        // which row within the wave
    const int l    = lane & 31;        // lane within the row
    const int p = blockIdx.x * 8 + wave * 2 + half;
    if (p >= P) return;

    const int d = l * 4;
    // broadcast weights (cache-resident)
    const nfloat4 we  = *(const nfloat4*)(ws + d);
    const nfloat4 wne = *(const nfloat4*)(ws + DIM + d);
    const nfloat4 wnr = *(const nfloat4*)(ws + 2 * DIM + d);
    const float   c   = ws[3 * DIM];

    const nfloat4 e4 = *(const nfloat4*)(ent + (size_t)p * DIM + d);
    const size_t rowK = ((size_t)p * KN) * DIM + d;
    nfloat4 ne4[KN], nr4[KN];
    #pragma unroll
    for (int k = 0; k < KN; ++k) {
        ne4[k] = *(const nfloat4*)(ne + rowK + (size_t)k * DIM);
        nr4[k] = *(const nfloat4*)(nr + rowK + (size_t)k * DIM);
    }

    // per-lane partial dot products
    float red[KN + 1];
    red[0] = dot4(e4, we);
    #pragma unroll
    for (int k = 0; k < KN; ++k)
        red[k + 1] = dot4(ne4[k], wne) + dot4(nr4[k], wnr);

    // 5-step butterfly within each 32-lane half (xor offsets < 32 stay in-half)
    #pragma unroll
    for (int j = 0; j < KN + 1; ++j) {
        float v = red[j];
        #pragma unroll
        for (int off = 16; off >= 1; off >>= 1) v += __shfl_xor(v, off, 64);
        red[j] = v;
    }

    // softmax over K=5 (redundant in every lane of the half; all agree)
    float logit[KN];
    float m = -INFINITY;
    #pragma unroll
    for (int k = 0; k < KN; ++k) {
        logit[k] = red[k + 1] + red[0] + c;
        m = fmaxf(m, logit[k]);
    }
    float ex[KN], s = 0.f;
    #pragma unroll
    for (int k = 0; k < KN; ++k) { ex[k] = __expf(logit[k] - m); s += ex[k]; }
    const float inv = 1.f / s;

    // attention-weighted neighbor sum from registers (no re-read of ne)
    nfloat4 acc = {0.f, 0.f, 0.f, 0.f};
    #pragma unroll
    for (int k = 0; k < KN; ++k) {
        const float a = ex[k] * inv;
        acc.x += a * ne4[k].x;
        acc.y += a * ne4[k].y;
        acc.z += a * ne4[k].z;
        acc.w += a * ne4[k].w;
    }

    float* orow = out + (size_t)p * (2 * DIM);
    __builtin_nontemporal_store(e4,  (nfloat4*)(orow + d));
    __builtin_nontemporal_store(acc, (nfloat4*)(orow + DIM + d));
}

extern "C" void kernel_launch(void* const* d_in, const int* in_sizes, int n_in,
                              void* d_out, int out_size, void* d_ws, size_t ws_size,
                              hipStream_t stream) {
    const float* ent = (const float*)d_in[0];
    const float* ne  = (const float*)d_in[1];
    const float* nr  = (const float*)d_in[2];
    const float* W1  = (const float*)d_in[3];
    const float* b1  = (const float*)d_in[4];
    const float* W2  = (const float*)d_in[5];
    const float* b2  = (const float*)d_in[6];
    float* out = (float*)d_out;
    float* ws  = (float*)d_ws;

    const int P = in_sizes[0] / DIM;  // B*N rows

    kgat_prep<<<(3 * DIM + 1 + 3) / 4, 256, 0, stream>>>(W1, b1, W2, b2, ws);
    kgat_main<<<(P + 7) / 8, 256, 0, stream>>>(ent, ne, nr, ws, out, P);
}